// Round 20
// baseline (105.763 us; speedup 1.0000x reference)
//
#include <hip/hip_runtime.h>
#include <stdint.h>

#define NHEAD 12
#define DKH   64
#define BB    2
#define SS    2048
#define DMOD  768
#define MTOT  (BB*SS)          // 4096
#define NCHUNK 2               // KV split (r10-proven)
#define CHS   (SS/NCHUNK)      // 1024 kv per chunk
#define QBLK  128
#define NT    (CHS/64)         // 16 kv tiles per block

typedef __attribute__((ext_vector_type(8)))  _Float16 half8;
typedef __attribute__((ext_vector_type(4)))  _Float16 half4;
typedef __attribute__((ext_vector_type(2)))  __fp16   fp16x2;
typedef __attribute__((ext_vector_type(4)))  float    f32x4;
typedef __attribute__((ext_vector_type(16))) float    f32x16;

typedef __attribute__((address_space(1))) const void gv_t;
typedef __attribute__((address_space(3))) void       lv_t;

__device__ inline float fexp2(float x) { return __builtin_amdgcn_exp2f(x); }
__device__ inline int pk2(float a, float b) {
    union { fp16x2 h; int i; } u;
    u.h = __builtin_amdgcn_cvt_pkrtz(a, b);
    return u.i;
}

// ---------------- fused f32 -> f16 converts: x + 4 weight matrices, one launch ----------------
__global__ void k_cvtall(const float* __restrict__ x,
                         const float* __restrict__ w0, const float* __restrict__ w1,
                         const float* __restrict__ w2, const float* __restrict__ w3,
                         _Float16* __restrict__ xb,
                         _Float16* __restrict__ o0, _Float16* __restrict__ o1,
                         _Float16* __restrict__ o2, _Float16* __restrict__ o3) {
    const float* in; _Float16* out; int base;
    int blk = blockIdx.x;
    if (blk < 3072)      { in = x;  out = xb; base = blk; }
    else if (blk < 3648) { in = w0; out = o0; base = blk - 3072; }
    else if (blk < 4224) { in = w1; out = o1; base = blk - 3648; }
    else if (blk < 4800) { in = w2; out = o2; base = blk - 4224; }
    else                 { in = w3; out = o3; base = blk - 4800; }
    int i = (base * 256 + threadIdx.x) * 4;
    float4 v = *(const float4*)(in + i);
    half4 o;
    o.x = (_Float16)v.x; o.y = (_Float16)v.y; o.z = (_Float16)v.z; o.w = (_Float16)v.w;
    *(half4*)(out + i) = o;
}

// ---------------- GEMM: C = A(M,K) * B(N,K)^T, fp16 in, f32 accum, BK=64 ----------------
// ROUND-14/10 PROVEN: 128x128 tile, single-buffered 32KB LDS. Falsified variants:
// r11 dbuf (−8.5us), r13 merge-fusion (−12.8us), r15 BM=64 retile (−1.5us).
template<int MODE>
__global__ __launch_bounds__(256, 2) void k_gemm(
    const _Float16* __restrict__ A, const _Float16* __restrict__ Bm,
    const float* __restrict__ bias0, const float* __restrict__ bias1, const float* __restrict__ bias2,
    float* __restrict__ outF,
    _Float16* __restrict__ Qd, _Float16* __restrict__ Kd, _Float16* __restrict__ Vtd,
    int K, int Ncols)
{
    __shared__ _Float16 As[128 * 64];   // 16KB
    __shared__ _Float16 Bs[128 * 64];   // 16KB
    const int tid = threadIdx.x;
    const int w = tid >> 6, l = tid & 63, lr = l & 15, lg = l >> 4;
    const int bm = blockIdx.y * 128, bn = blockIdx.x * 128;
    const int wm = (w >> 1) * 64, wn = (w & 1) * 64;
    f32x4 acc[4][4] = {};

    for (int k0 = 0; k0 < K; k0 += 64) {
        __syncthreads();
#pragma unroll
        for (int i = 0; i < 4; ++i) {
            int o  = w * 4096 + i * 1024 + l * 16;    // linear LDS byte offset
            int lo = o ^ (((o >> 7) & 7) << 4);       // pre-swizzled source
            int row = lo >> 7;
            int colb = lo & 127;
            __builtin_amdgcn_global_load_lds(
                (gv_t*)((const char*)A + ((size_t)(bm + row) * K + k0) * 2 + colb),
                (lv_t*)((char*)As + o), 16, 0, 0);
            __builtin_amdgcn_global_load_lds(
                (gv_t*)((const char*)Bm + ((size_t)(bn + row) * K + k0) * 2 + colb),
                (lv_t*)((char*)Bs + o), 16, 0, 0);
        }
        __syncthreads();
#pragma unroll
        for (int kk = 0; kk < 2; ++kk) {
            half8 af[4], bf[4];
#pragma unroll
            for (int f = 0; f < 4; ++f) {
                int ob = ((wm + f * 16 + lr) * 128 + kk * 64 + lg * 16) ^ ((lr & 7) << 4);
                af[f] = *(const half8*)((const char*)As + ob);
                int ob2 = ((wn + f * 16 + lr) * 128 + kk * 64 + lg * 16) ^ ((lr & 7) << 4);
                bf[f] = *(const half8*)((const char*)Bs + ob2);
            }
            __builtin_amdgcn_s_setprio(1);
#pragma unroll
            for (int fm = 0; fm < 4; ++fm)
#pragma unroll
                for (int fn = 0; fn < 4; ++fn)
                    acc[fm][fn] = __builtin_amdgcn_mfma_f32_16x16x32_f16(af[fm], bf[fn], acc[fm][fn], 0, 0, 0);
            __builtin_amdgcn_s_setprio(0);
        }
    }

#pragma unroll
    for (int fm = 0; fm < 4; ++fm) {
#pragma unroll
        for (int fn = 0; fn < 4; ++fn) {
            int n = bn + wn + fn * 16 + lr;
            if (MODE == 0) {
                float bia = bias0[n];
#pragma unroll
                for (int j = 0; j < 4; ++j) {
                    int m = bm + wm + fm * 16 + lg * 4 + j;
                    outF[(size_t)m * Ncols + n] = acc[fm][fn][j] + bia;
                }
            } else {
                int qkv = n / 768, nn = n - qkv * 768;
                const float* bp = (qkv == 0) ? bias0 : (qkv == 1 ? bias1 : bias2);
                float bia = bp[nn];
                int h = nn >> 6, dk = nn & 63;
                int m0 = bm + wm + fm * 16 + lg * 4;
                int b = m0 >> 11;
                int s0 = m0 & 2047;
                size_t head = (size_t)b * NHEAD + h;
                if (qkv == 2) {
                    half4 pk;
#pragma unroll
                    for (int j = 0; j < 4; ++j) pk[j] = (_Float16)(acc[fm][fn][j] + bia);
                    *(half4*)(Vtd + (head * DKH + dk) * SS + s0) = pk;
                } else {
                    _Float16* dst = (qkv == 0) ? Qd : Kd;
                    float qsc = (qkv == 0) ? 0.18033688011f : 1.0f;  // 0.125*log2(e) folded into Q
#pragma unroll
                    for (int j = 0; j < 4; ++j)
                        dst[(head * SS + (s0 + j)) * DKH + dk] = (_Float16)((acc[fm][fn][j] + bia) * qsc);
                }
            }
        }
    }
}

// ---------------- flash attention partial, 32x32 MFMA, swapped operands ----------------
// ROUND-19 PROVEN KERNEL (46.0us: XCD swizzle + mask pre-scan) + softmax VALU cut:
// (a) max tree via 3-way-nested fmax (clang -> v_max3_f32, T17);
// (b) row sum via v_dot2_f32_f16 on the SAME packed-f16 P words PV consumes
//     (16 dot2 replaces 31-op f32 add tree + frees the t[16] transient).
//     Guarded by __has_builtin; fallback = proven f32 tree.
__global__ __launch_bounds__(256, 3) void k_attn(
    const _Float16* __restrict__ Qd, const _Float16* __restrict__ Kd,
    const _Float16* __restrict__ Vtd, const int* __restrict__ mask,
    _Float16* __restrict__ Opart, float* __restrict__ Mpart, float* __restrict__ Lpart)
{
    __shared__ _Float16 Ks[2 * 64 * 64];   // [buf][kv][dk], rows 128B, XOR-swizzled
    __shared__ _Float16 Vs[2 * 64 * 64];   // [buf][dv][kv], rows 128B, XOR-swizzled
    const int tid = threadIdx.x, w = tid >> 6, l = tid & 63;
    const int lq = l & 31, lhi = l >> 5;
    // XCD swizzle: 768 blocks, 8 XCDs -> 96 consecutive gids per XCD = 3 heads
    const int F = blockIdx.x;
    const int gid = (F & 7) * 96 + (F >> 3);
    const int head  = gid >> 5;            // b*12+h
    const int rem   = gid & 31;
    const int qt    = rem >> 1;            // 0..15
    const int chunk = rem & 1;             // 0..1
    const int b = head / NHEAD;
    const char* Qh = (const char*)(Qd + (size_t)head * SS * DKH);
    const char* Kh = (const char*)(Kd + (size_t)head * SS * DKH) + (size_t)chunk * CHS * 128;
    const char* Vh = (const char*)(Vtd + (size_t)head * DKH * SS);
    const int vcb = chunk * CHS * 2;       // byte offset into a V row

    const int q = qt * QBLK + w * 32 + lq;
    half8 qf[4];
#pragma unroll
    for (int kd = 0; kd < 4; ++kd)
        qf[kd] = *(const half8*)(Qh + ((size_t)q * 64 + kd * 16 + lhi * 8) * 2);

    // ---- mask pre-scan: one pipelined pass, wave-uniform fast flag ----
    int allone = 1;
#pragma unroll
    for (int kt = 0; kt < NT; ++kt)
        allone &= (mask[b * SS + chunk * CHS + kt * 64 + l] != 0);
    const bool fast = __all(allone);

    f32x16 accO[2] = {};                   // O^T[dv = ds*32 + rowmap][q = lq]
    float m = -__builtin_inff(), lsum = 0.f;

    auto STAGE = [&](int kt2, int buf) {
#pragma unroll
        for (int i = 0; i < 2; ++i) {
            int o  = w * 2048 + i * 1024 + l * 16;
            int lo = o ^ (((o >> 7) & 7) << 4);       // pre-swizzled source offset
            __builtin_amdgcn_global_load_lds(
                (gv_t*)(Kh + (size_t)kt2 * 8192 + lo),
                (lv_t*)((char*)Ks + buf * 8192 + w * 2048 + i * 1024), 16, 0, 0);
            int dv = lo >> 7, inner = lo & 127;
            __builtin_amdgcn_global_load_lds(
                (gv_t*)(Vh + (size_t)dv * 4096 + vcb + kt2 * 128 + inner),
                (lv_t*)((char*)Vs + buf * 8192 + w * 2048 + i * 1024), 16, 0, 0);
        }
    };

    STAGE(0, 0);
    int cur = 0;

    for (int kt = 0; kt < NT; ++kt) {
        __syncthreads();                   // staging of buf[cur] complete, reads of buf[cur^1] done
        if (kt < NT - 1) STAGE(kt + 1, cur ^ 1);
        unsigned long long bal = ~0ull;
        if (!fast) {
            int mv = mask[b * SS + chunk * CHS + kt * 64 + l];
            bal = __ballot(mv != 0);
        }
        const char* kb = (const char*)Ks + cur * 8192;
        const char* vb = (const char*)Vs + cur * 8192;

        // ---- S^T = K Q^T : s0 = kv 0..31, s1 = kv 32..63, cols q ----
        f32x16 s0 = {}, s1 = {};
#pragma unroll
        for (int kd = 0; kd < 4; ++kd) {
            int col = kd * 32 + lhi * 16;
            int ob0 = (lq * 128 + col) ^ ((lq & 7) << 4);
            half8 kf0 = *(const half8*)(kb + ob0);
            s0 = __builtin_amdgcn_mfma_f32_32x32x16_f16(kf0, qf[kd], s0, 0, 0, 0);
            int ob1 = ((32 + lq) * 128 + col) ^ ((lq & 7) << 4);
            half8 kf1 = *(const half8*)(kb + ob1);
            s1 = __builtin_amdgcn_mfma_f32_32x32x16_f16(kf1, qf[kd], s1, 0, 0, 0);
        }

        // ---- mask (skipped entirely on the fast path) ----
        if (!fast && bal != ~0ull) {
#pragma unroll
            for (int r = 0; r < 16; ++r) {
                int kv0 = (r & 3) + 8 * (r >> 2) + 4 * lhi;
                if (!((bal >> kv0) & 1))        s0[r] = -__builtin_inff();
                if (!((bal >> (kv0 + 32)) & 1)) s1[r] = -__builtin_inff();
            }
        }

        // ---- row max: pairwise merge + v_max3 tree + one shfl_xor(32) ----
        float a[16];
#pragma unroll
        for (int i = 0; i < 16; ++i) a[i] = fmaxf(s0[i], s1[i]);
        float v0 = fmaxf(fmaxf(a[0],  a[1]),  a[2]);
        float v1 = fmaxf(fmaxf(a[3],  a[4]),  a[5]);
        float v2 = fmaxf(fmaxf(a[6],  a[7]),  a[8]);
        float v3 = fmaxf(fmaxf(a[9],  a[10]), a[11]);
        float v4 = fmaxf(fmaxf(a[12], a[13]), a[14]);
        float v5 = fmaxf(fmaxf(v0, v1), v2);
        float v6 = fmaxf(fmaxf(v3, v4), a[15]);
        float tmax = fmaxf(v5, v6);
        float pmax = fmaxf(tmax, __shfl_xor(tmax, 32, 64));

        // ---- defer-max (T13): skip rescale when growth <= 3 (P <= 8) ----
        if (!__all(pmax <= m + 3.0f)) {
            float mnew = fmaxf(m, pmax);
            float f = fexp2(m - mnew);
            m = mnew; lsum *= f;
            accO[0] *= f; accO[1] *= f;
        }
        float mex = fmaxf(m, -1e30f);      // guard all-masked rows

        // ---- P = exp2(S - mex) ----
#pragma unroll
        for (int i = 0; i < 16; ++i) { s0[i] = fexp2(s0[i] - mex); s1[i] = fexp2(s1[i] - mex); }

        // ---- pack P to f16; row sum from the SAME packed values; permlane redistribute ----
        union PF { int w[4]; half8 h; } pf[4];
        float part = 0.f;
#if defined(__has_builtin) && __has_builtin(__builtin_amdgcn_fdot2)
        const fp16x2 one2 = { (__fp16)1.0f, (__fp16)1.0f };
#endif
        {
            int W[8];
#pragma unroll
            for (int mm = 0; mm < 8; ++mm) W[mm] = pk2(s0[2 * mm], s0[2 * mm + 1]);
#if defined(__has_builtin) && __has_builtin(__builtin_amdgcn_fdot2)
#pragma unroll
            for (int mm = 0; mm < 8; ++mm) {
                union { int i; fp16x2 h; } u; u.i = W[mm];
                part = __builtin_amdgcn_fdot2(u.h, one2, part, false);
            }
#else
#pragma unroll
            for (int i = 0; i < 16; ++i) part += s0[i];
#endif
            asm("v_permlane32_swap_b32 %0, %1" : "+v"(W[0]), "+v"(W[2]));
            asm("v_permlane32_swap_b32 %0, %1" : "+v"(W[1]), "+v"(W[3]));
            asm("v_permlane32_swap_b32 %0, %1" : "+v"(W[4]), "+v"(W[6]));
            asm("v_permlane32_swap_b32 %0, %1" : "+v"(W[5]), "+v"(W[7]));
            pf[0].w[0] = W[0]; pf[0].w[1] = W[1]; pf[0].w[2] = W[2]; pf[0].w[3] = W[3];
            pf[1].w[0] = W[4]; pf[1].w[1] = W[5]; pf[1].w[2] = W[6]; pf[1].w[3] = W[7];
#pragma unroll
            for (int mm = 0; mm < 8; ++mm) W[mm] = pk2(s1[2 * mm], s1[2 * mm + 1]);
#if defined(__has_builtin) && __has_builtin(__builtin_amdgcn_fdot2)
#pragma unroll
            for (int mm = 0; mm < 8; ++mm) {
                union { int i; fp16x2 h; } u; u.i = W[mm];
                part = __builtin_amdgcn_fdot2(u.h, one2, part, false);
            }
#else
#pragma unroll
            for (int i = 0; i < 16; ++i) part += s1[i];
#endif
            asm("v_permlane32_swap_b32 %0, %1" : "+v"(W[0]), "+v"(W[2]));
            asm("v_permlane32_swap_b32 %0, %1" : "+v"(W[1]), "+v"(W[3]));
            asm("v_permlane32_swap_b32 %0, %1" : "+v"(W[4]), "+v"(W[6]));
            asm("v_permlane32_swap_b32 %0, %1" : "+v"(W[5]), "+v"(W[7]));
            pf[2].w[0] = W[0]; pf[2].w[1] = W[1]; pf[2].w[2] = W[2]; pf[2].w[3] = W[3];
            pf[3].w[0] = W[4]; pf[3].w[1] = W[5]; pf[3].w[2] = W[6]; pf[3].w[3] = W[7];
        }
        lsum += part + __shfl_xor(part, 32, 64);

        // ---- O^T += Vt P : 2 dv-subtiles x 4 kv-chunks of 16 ----
#pragma unroll
        for (int cc = 0; cc < 4; ++cc) {
            int col = cc * 32 + lhi * 16;
#pragma unroll
            for (int ds = 0; ds < 2; ++ds) {
                int vrow = ds * 32 + lq;
                int ob = (vrow * 128 + col) ^ ((lq & 7) << 4);
                half8 vf = *(const half8*)(vb + ob);
                accO[ds] = __builtin_amdgcn_mfma_f32_32x32x16_f16(vf, pf[cc].h, accO[ds], 0, 0, 0);
            }
        }
        cur ^= 1;
    }

    // ---- epilogue: unnormalized partial O (f16) + m,l ----
    const size_t prow = (size_t)(chunk * BB * NHEAD + head) * SS;
    if (lhi == 0) { Mpart[prow + q] = m; Lpart[prow + q] = lsum; }
#pragma unroll
    for (int ds = 0; ds < 2; ++ds)
#pragma unroll
        for (int rq = 0; rq < 4; ++rq) {
            half4 hv;
#pragma unroll
            for (int j = 0; j < 4; ++j) hv[j] = (_Float16)accO[ds][rq * 4 + j];
            *(half4*)(Opart + (prow + q) * DKH + ds * 32 + rq * 8 + lhi * 4) = hv;
        }
}

// ---------------- merge partials -> ctx (fp16, [b][s][h*64+dv]) ----------------
__global__ __launch_bounds__(256) void k_merge(
    const _Float16* __restrict__ Opart, const float* __restrict__ Mpart,
    const float* __restrict__ Lpart, _Float16* __restrict__ Ctx)
{
    int row  = blockIdx.x * 4 + (threadIdx.x >> 6);   // head*2048 + q
    int lane = threadIdx.x & 63;
    int head = row >> 11, q = row & 2047;
    int b = head / NHEAD, h = head - b * NHEAD;
    float m[NCHUNK], lv[NCHUNK], M = -__builtin_inff();
#pragma unroll
    for (int c = 0; c < NCHUNK; ++c) {
        size_t pr = (size_t)(c * BB * NHEAD + head) * SS + q;
        m[c] = Mpart[pr]; lv[c] = Lpart[pr];
        M = fmaxf(M, m[c]);
    }
    float outv = 0.f;
    if (M > -1e37f) {
        float L = 0.f, acc = 0.f;
#pragma unroll
        for (int c = 0; c < NCHUNK; ++c) {
            float wgt = fexp2(m[c] - M);
            L += lv[c] * wgt;
            acc += wgt * (float)Opart[((size_t)(c * BB * NHEAD + head) * SS + q) * DKH + lane];
        }
        outv = acc / L;
    }
    Ctx[((size_t)(b * SS) + q) * DMOD + h * DKH + lane] = (_Float16)outv;
}

// ---------------- launcher ----------------
extern "C" void kernel_launch(void* const* d_in, const int* in_sizes, int n_in,
                              void* d_out, int out_size, void* d_ws, size_t ws_size,
                              hipStream_t stream) {
    const float* x  = (const float*)d_in[0];
    const int*  msk = (const int*)d_in[1];
    const float* Wq = (const float*)d_in[2];
    const float* bq = (const float*)d_in[3];
    const float* Wk = (const float*)d_in[4];
    const float* bk = (const float*)d_in[5];
    const float* Wv = (const float*)d_in[6];
    const float* bv = (const float*)d_in[7];
    const float* Wo = (const float*)d_in[8];
    const float* bo = (const float*)d_in[9];

    char* ws = (char*)d_ws;
    _Float16* Xb   = (_Float16*)(ws);                 // 4096x768            6,291,456 B
    _Float16* Wqkv = (_Float16*)(ws + 6291456);       // 2304x768            3,538,944 B
    _Float16* Wob  = (_Float16*)(ws + 9830400);       // 768x768             1,179,648 B
    _Float16* Qd   = (_Float16*)(ws + 11010048);      // 24 x 2048 x 64      6,291,456 B
    _Float16* Kd   = (_Float16*)(ws + 17301504);      // 24 x 2048 x 64      6,291,456 B
    _Float16* Vtd  = (_Float16*)(ws + 23592960);      // 24 x 64 x 2048      6,291,456 B
    _Float16* Ctxb = (_Float16*)(ws + 29884416);      // 4096x768            6,291,456 B
    _Float16* Opart= (_Float16*)(ws + 36175872);      // 2 x 24 x 2048 x 64 12,582,912 B
    float*    Mpart= (float*)   (ws + 48758784);      // 2 x 24 x 2048         393,216 B
    float*    Lpart= (float*)   (ws + 49152000);      // 2 x 24 x 2048         393,216 B

    k_cvtall<<<5376, 256, 0, stream>>>(x, Wq, Wk, Wv, Wo,
                                       Xb, Wqkv, Wqkv + 589824, Wqkv + 1179648, Wob);

    k_gemm<1><<<dim3(18, 32), 256, 0, stream>>>(Xb, Wqkv, bq, bk, bv,
                                                nullptr, Qd, Kd, Vtd, DMOD, 0);
    k_attn<<<dim3(24 * 16 * NCHUNK), 256, 0, stream>>>(Qd, Kd, Vtd, msk, Opart, Mpart, Lpart);
    k_merge<<<12288, 256, 0, stream>>>(Opart, Mpart, Lpart, Ctxb);
    k_gemm<0><<<dim3(6, 32), 256, 0, stream>>>(Ctxb, Wob, bo, nullptr, nullptr,
                                               (float*)d_out, nullptr, nullptr, nullptr,
                                               DMOD, DMOD);
}

// Round 21
// 104.497 us; speedup vs baseline: 1.0121x; 1.0121x over previous
//
#include <hip/hip_runtime.h>
#include <stdint.h>

#define NHEAD 12
#define DKH   64
#define BB    2
#define SS    2048
#define DMOD  768
#define MTOT  (BB*SS)          // 4096
#define NCHUNK 2               // KV split (r10-proven)
#define CHS   (SS/NCHUNK)      // 1024 kv per chunk
#define QBLK  128
#define NT    (CHS/64)         // 16 kv tiles per block

typedef __attribute__((ext_vector_type(8)))  _Float16 half8;
typedef __attribute__((ext_vector_type(4)))  _Float16 half4;
typedef __attribute__((ext_vector_type(2)))  __fp16   fp16x2;
typedef __attribute__((ext_vector_type(4)))  float    f32x4;
typedef __attribute__((ext_vector_type(16))) float    f32x16;

typedef __attribute__((address_space(1))) const void gv_t;
typedef __attribute__((address_space(3))) void       lv_t;

__device__ inline float fexp2(float x) { return __builtin_amdgcn_exp2f(x); }
__device__ inline int pk2(float a, float b) {
    union { fp16x2 h; int i; } u;
    u.h = __builtin_amdgcn_cvt_pkrtz(a, b);
    return u.i;
}

// ---------------- fused f32 -> f16 converts: x + 4 weight matrices, one launch ----------------
__global__ void k_cvtall(const float* __restrict__ x,
                         const float* __restrict__ w0, const float* __restrict__ w1,
                         const float* __restrict__ w2, const float* __restrict__ w3,
                         _Float16* __restrict__ xb,
                         _Float16* __restrict__ o0, _Float16* __restrict__ o1,
                         _Float16* __restrict__ o2, _Float16* __restrict__ o3) {
    const float* in; _Float16* out; int base;
    int blk = blockIdx.x;
    if (blk < 3072)      { in = x;  out = xb; base = blk; }
    else if (blk < 3648) { in = w0; out = o0; base = blk - 3072; }
    else if (blk < 4224) { in = w1; out = o1; base = blk - 3648; }
    else if (blk < 4800) { in = w2; out = o2; base = blk - 4224; }
    else                 { in = w3; out = o3; base = blk - 4800; }
    int i = (base * 256 + threadIdx.x) * 4;
    float4 v = *(const float4*)(in + i);
    half4 o;
    o.x = (_Float16)v.x; o.y = (_Float16)v.y; o.z = (_Float16)v.z; o.w = (_Float16)v.w;
    *(half4*)(out + i) = o;
}

// ---------------- GEMM: C = A(M,K) * B(N,K)^T, fp16 in, f32 accum, BK=64 ----------------
// ROUND-14/10 PROVEN: 128x128 tile, single-buffered 32KB LDS. Falsified variants:
// r11 dbuf (−8.5us), r13 merge-fusion (−12.8us), r15 BM=64 retile (−1.5us).
template<int MODE>
__global__ __launch_bounds__(256, 2) void k_gemm(
    const _Float16* __restrict__ A, const _Float16* __restrict__ Bm,
    const float* __restrict__ bias0, const float* __restrict__ bias1, const float* __restrict__ bias2,
    float* __restrict__ outF,
    _Float16* __restrict__ Qd, _Float16* __restrict__ Kd, _Float16* __restrict__ Vtd,
    int K, int Ncols)
{
    __shared__ _Float16 As[128 * 64];   // 16KB
    __shared__ _Float16 Bs[128 * 64];   // 16KB
    const int tid = threadIdx.x;
    const int w = tid >> 6, l = tid & 63, lr = l & 15, lg = l >> 4;
    const int bm = blockIdx.y * 128, bn = blockIdx.x * 128;
    const int wm = (w >> 1) * 64, wn = (w & 1) * 64;
    f32x4 acc[4][4] = {};

    for (int k0 = 0; k0 < K; k0 += 64) {
        __syncthreads();
#pragma unroll
        for (int i = 0; i < 4; ++i) {
            int o  = w * 4096 + i * 1024 + l * 16;    // linear LDS byte offset
            int lo = o ^ (((o >> 7) & 7) << 4);       // pre-swizzled source
            int row = lo >> 7;
            int colb = lo & 127;
            __builtin_amdgcn_global_load_lds(
                (gv_t*)((const char*)A + ((size_t)(bm + row) * K + k0) * 2 + colb),
                (lv_t*)((char*)As + o), 16, 0, 0);
            __builtin_amdgcn_global_load_lds(
                (gv_t*)((const char*)Bm + ((size_t)(bn + row) * K + k0) * 2 + colb),
                (lv_t*)((char*)Bs + o), 16, 0, 0);
        }
        __syncthreads();
#pragma unroll
        for (int kk = 0; kk < 2; ++kk) {
            half8 af[4], bf[4];
#pragma unroll
            for (int f = 0; f < 4; ++f) {
                int ob = ((wm + f * 16 + lr) * 128 + kk * 64 + lg * 16) ^ ((lr & 7) << 4);
                af[f] = *(const half8*)((const char*)As + ob);
                int ob2 = ((wn + f * 16 + lr) * 128 + kk * 64 + lg * 16) ^ ((lr & 7) << 4);
                bf[f] = *(const half8*)((const char*)Bs + ob2);
            }
            __builtin_amdgcn_s_setprio(1);
#pragma unroll
            for (int fm = 0; fm < 4; ++fm)
#pragma unroll
                for (int fn = 0; fn < 4; ++fn)
                    acc[fm][fn] = __builtin_amdgcn_mfma_f32_16x16x32_f16(af[fm], bf[fn], acc[fm][fn], 0, 0, 0);
            __builtin_amdgcn_s_setprio(0);
        }
    }

#pragma unroll
    for (int fm = 0; fm < 4; ++fm) {
#pragma unroll
        for (int fn = 0; fn < 4; ++fn) {
            int n = bn + wn + fn * 16 + lr;
            if (MODE == 0) {
                float bia = bias0[n];
#pragma unroll
                for (int j = 0; j < 4; ++j) {
                    int m = bm + wm + fm * 16 + lg * 4 + j;
                    outF[(size_t)m * Ncols + n] = acc[fm][fn][j] + bia;
                }
            } else {
                int qkv = n / 768, nn = n - qkv * 768;
                const float* bp = (qkv == 0) ? bias0 : (qkv == 1 ? bias1 : bias2);
                float bia = bp[nn];
                int h = nn >> 6, dk = nn & 63;
                int m0 = bm + wm + fm * 16 + lg * 4;
                int b = m0 >> 11;
                int s0 = m0 & 2047;
                size_t head = (size_t)b * NHEAD + h;
                if (qkv == 2) {
                    half4 pk;
#pragma unroll
                    for (int j = 0; j < 4; ++j) pk[j] = (_Float16)(acc[fm][fn][j] + bia);
                    *(half4*)(Vtd + (head * DKH + dk) * SS + s0) = pk;
                } else {
                    _Float16* dst = (qkv == 0) ? Qd : Kd;
                    float qsc = (qkv == 0) ? 0.18033688011f : 1.0f;  // 0.125*log2(e) folded into Q
#pragma unroll
                    for (int j = 0; j < 4; ++j)
                        dst[(head * SS + (s0 + j)) * DKH + dk] = (_Float16)((acc[fm][fn][j] + bia) * qsc);
                }
            }
        }
    }
}

// ---------------- flash attention partial, 32x32 MFMA, swapped operands ----------------
// ROUND-19 PROVEN KERNEL (46.0us, total 104.79): XCD swizzle + mask pre-scan +
// LDS dbuf K/V + VALU lsum tree + defer-max, (256,3). r20's fdot2 row-sum
// REGRESSED +2.1us: it swapped the depth-5 f32 add tree for a depth-16 serial
// fdot2 chain — in a latency-bound kernel, dependency depth > op count.
__global__ __launch_bounds__(256, 3) void k_attn(
    const _Float16* __restrict__ Qd, const _Float16* __restrict__ Kd,
    const _Float16* __restrict__ Vtd, const int* __restrict__ mask,
    _Float16* __restrict__ Opart, float* __restrict__ Mpart, float* __restrict__ Lpart)
{
    __shared__ _Float16 Ks[2 * 64 * 64];   // [buf][kv][dk], rows 128B, XOR-swizzled
    __shared__ _Float16 Vs[2 * 64 * 64];   // [buf][dv][kv], rows 128B, XOR-swizzled
    const int tid = threadIdx.x, w = tid >> 6, l = tid & 63;
    const int lq = l & 31, lhi = l >> 5;
    // XCD swizzle: 768 blocks, 8 XCDs -> 96 consecutive gids per XCD = 3 heads
    const int F = blockIdx.x;
    const int gid = (F & 7) * 96 + (F >> 3);
    const int head  = gid >> 5;            // b*12+h
    const int rem   = gid & 31;
    const int qt    = rem >> 1;            // 0..15
    const int chunk = rem & 1;             // 0..1
    const int b = head / NHEAD;
    const char* Qh = (const char*)(Qd + (size_t)head * SS * DKH);
    const char* Kh = (const char*)(Kd + (size_t)head * SS * DKH) + (size_t)chunk * CHS * 128;
    const char* Vh = (const char*)(Vtd + (size_t)head * DKH * SS);
    const int vcb = chunk * CHS * 2;       // byte offset into a V row

    const int q = qt * QBLK + w * 32 + lq;
    half8 qf[4];
#pragma unroll
    for (int kd = 0; kd < 4; ++kd)
        qf[kd] = *(const half8*)(Qh + ((size_t)q * 64 + kd * 16 + lhi * 8) * 2);

    // ---- mask pre-scan: one pipelined pass, wave-uniform fast flag ----
    int allone = 1;
#pragma unroll
    for (int kt = 0; kt < NT; ++kt)
        allone &= (mask[b * SS + chunk * CHS + kt * 64 + l] != 0);
    const bool fast = __all(allone);

    f32x16 accO[2] = {};                   // O^T[dv = ds*32 + rowmap][q = lq]
    float m = -__builtin_inff(), lsum = 0.f;

    auto STAGE = [&](int kt2, int buf) {
#pragma unroll
        for (int i = 0; i < 2; ++i) {
            int o  = w * 2048 + i * 1024 + l * 16;
            int lo = o ^ (((o >> 7) & 7) << 4);       // pre-swizzled source offset
            __builtin_amdgcn_global_load_lds(
                (gv_t*)(Kh + (size_t)kt2 * 8192 + lo),
                (lv_t*)((char*)Ks + buf * 8192 + w * 2048 + i * 1024), 16, 0, 0);
            int dv = lo >> 7, inner = lo & 127;
            __builtin_amdgcn_global_load_lds(
                (gv_t*)(Vh + (size_t)dv * 4096 + vcb + kt2 * 128 + inner),
                (lv_t*)((char*)Vs + buf * 8192 + w * 2048 + i * 1024), 16, 0, 0);
        }
    };

    STAGE(0, 0);
    int cur = 0;

    for (int kt = 0; kt < NT; ++kt) {
        __syncthreads();                   // staging of buf[cur] complete, reads of buf[cur^1] done
        if (kt < NT - 1) STAGE(kt + 1, cur ^ 1);
        unsigned long long bal = ~0ull;
        if (!fast) {
            int mv = mask[b * SS + chunk * CHS + kt * 64 + l];
            bal = __ballot(mv != 0);
        }
        const char* kb = (const char*)Ks + cur * 8192;
        const char* vb = (const char*)Vs + cur * 8192;

        // ---- S^T = K Q^T : s0 = kv 0..31, s1 = kv 32..63, cols q ----
        f32x16 s0 = {}, s1 = {};
#pragma unroll
        for (int kd = 0; kd < 4; ++kd) {
            int col = kd * 32 + lhi * 16;
            int ob0 = (lq * 128 + col) ^ ((lq & 7) << 4);
            half8 kf0 = *(const half8*)(kb + ob0);
            s0 = __builtin_amdgcn_mfma_f32_32x32x16_f16(kf0, qf[kd], s0, 0, 0, 0);
            int ob1 = ((32 + lq) * 128 + col) ^ ((lq & 7) << 4);
            half8 kf1 = *(const half8*)(kb + ob1);
            s1 = __builtin_amdgcn_mfma_f32_32x32x16_f16(kf1, qf[kd], s1, 0, 0, 0);
        }

        // ---- mask (skipped entirely on the fast path) ----
        if (!fast && bal != ~0ull) {
#pragma unroll
            for (int r = 0; r < 16; ++r) {
                int kv0 = (r & 3) + 8 * (r >> 2) + 4 * lhi;
                if (!((bal >> kv0) & 1))        s0[r] = -__builtin_inff();
                if (!((bal >> (kv0 + 32)) & 1)) s1[r] = -__builtin_inff();
            }
        }

        // ---- row max: in-lane tree (32 vals) + one shfl_xor(32) ----
        float t[16];
#pragma unroll
        for (int i = 0; i < 16; ++i) t[i] = fmaxf(s0[i], s1[i]);
#pragma unroll
        for (int i = 0; i < 8; ++i) t[i] = fmaxf(t[i], t[i + 8]);
#pragma unroll
        for (int i = 0; i < 4; ++i) t[i] = fmaxf(t[i], t[i + 4]);
        t[0] = fmaxf(fmaxf(t[0], t[2]), fmaxf(t[1], t[3]));
        float pmax = fmaxf(t[0], __shfl_xor(t[0], 32, 64));

        // ---- defer-max (T13): skip rescale when growth <= 3 (P <= 8) ----
        if (!__all(pmax <= m + 3.0f)) {
            float mnew = fmaxf(m, pmax);
            float f = fexp2(m - mnew);
            m = mnew; lsum *= f;
            accO[0] *= f; accO[1] *= f;
        }
        float mex = fmaxf(m, -1e30f);      // guard all-masked rows

        // ---- P = exp2(S - mex); row sum ----
#pragma unroll
        for (int i = 0; i < 16; ++i) { s0[i] = fexp2(s0[i] - mex); s1[i] = fexp2(s1[i] - mex); }
#pragma unroll
        for (int i = 0; i < 16; ++i) t[i] = s0[i] + s1[i];
#pragma unroll
        for (int i = 0; i < 8; ++i) t[i] = t[i] + t[i + 8];
#pragma unroll
        for (int i = 0; i < 4; ++i) t[i] = t[i] + t[i + 4];
        t[0] = (t[0] + t[2]) + (t[1] + t[3]);
        lsum += t[0] + __shfl_xor(t[0], 32, 64);

        // ---- pack P to f16 + permlane32_swap redistribution -> PV B-operands ----
        union PF { int w[4]; half8 h; } pf[4];
        {
            int W[8];
#pragma unroll
            for (int mm = 0; mm < 8; ++mm) W[mm] = pk2(s0[2 * mm], s0[2 * mm + 1]);
            asm("v_permlane32_swap_b32 %0, %1" : "+v"(W[0]), "+v"(W[2]));
            asm("v_permlane32_swap_b32 %0, %1" : "+v"(W[1]), "+v"(W[3]));
            asm("v_permlane32_swap_b32 %0, %1" : "+v"(W[4]), "+v"(W[6]));
            asm("v_permlane32_swap_b32 %0, %1" : "+v"(W[5]), "+v"(W[7]));
            pf[0].w[0] = W[0]; pf[0].w[1] = W[1]; pf[0].w[2] = W[2]; pf[0].w[3] = W[3];
            pf[1].w[0] = W[4]; pf[1].w[1] = W[5]; pf[1].w[2] = W[6]; pf[1].w[3] = W[7];
#pragma unroll
            for (int mm = 0; mm < 8; ++mm) W[mm] = pk2(s1[2 * mm], s1[2 * mm + 1]);
            asm("v_permlane32_swap_b32 %0, %1" : "+v"(W[0]), "+v"(W[2]));
            asm("v_permlane32_swap_b32 %0, %1" : "+v"(W[1]), "+v"(W[3]));
            asm("v_permlane32_swap_b32 %0, %1" : "+v"(W[4]), "+v"(W[6]));
            asm("v_permlane32_swap_b32 %0, %1" : "+v"(W[5]), "+v"(W[7]));
            pf[2].w[0] = W[0]; pf[2].w[1] = W[1]; pf[2].w[2] = W[2]; pf[2].w[3] = W[3];
            pf[3].w[0] = W[4]; pf[3].w[1] = W[5]; pf[3].w[2] = W[6]; pf[3].w[3] = W[7];
        }

        // ---- O^T += Vt P : 2 dv-subtiles x 4 kv-chunks of 16 ----
#pragma unroll
        for (int cc = 0; cc < 4; ++cc) {
            int col = cc * 32 + lhi * 16;
#pragma unroll
            for (int ds = 0; ds < 2; ++ds) {
                int vrow = ds * 32 + lq;
                int ob = (vrow * 128 + col) ^ ((lq & 7) << 4);
                half8 vf = *(const half8*)(vb + ob);
                accO[ds] = __builtin_amdgcn_mfma_f32_32x32x16_f16(vf, pf[cc].h, accO[ds], 0, 0, 0);
            }
        }
        cur ^= 1;
    }

    // ---- epilogue: unnormalized partial O (f16) + m,l ----
    const size_t prow = (size_t)(chunk * BB * NHEAD + head) * SS;
    if (lhi == 0) { Mpart[prow + q] = m; Lpart[prow + q] = lsum; }
#pragma unroll
    for (int ds = 0; ds < 2; ++ds)
#pragma unroll
        for (int rq = 0; rq < 4; ++rq) {
            half4 hv;
#pragma unroll
            for (int j = 0; j < 4; ++j) hv[j] = (_Float16)accO[ds][rq * 4 + j];
            *(half4*)(Opart + (prow + q) * DKH + ds * 32 + rq * 8 + lhi * 4) = hv;
        }
}

// ---------------- merge partials -> ctx (fp16, [b][s][h*64+dv]) ----------------
__global__ __launch_bounds__(256) void k_merge(
    const _Float16* __restrict__ Opart, const float* __restrict__ Mpart,
    const float* __restrict__ Lpart, _Float16* __restrict__ Ctx)
{
    int row  = blockIdx.x * 4 + (threadIdx.x >> 6);   // head*2048 + q
    int lane = threadIdx.x & 63;
    int head = row >> 11, q = row & 2047;
    int b = head / NHEAD, h = head - b * NHEAD;
    float m[NCHUNK], lv[NCHUNK], M = -__builtin_inff();
#pragma unroll
    for (int c = 0; c < NCHUNK; ++c) {
        size_t pr = (size_t)(c * BB * NHEAD + head) * SS + q;
        m[c] = Mpart[pr]; lv[c] = Lpart[pr];
        M = fmaxf(M, m[c]);
    }
    float outv = 0.f;
    if (M > -1e37f) {
        float L = 0.f, acc = 0.f;
#pragma unroll
        for (int c = 0; c < NCHUNK; ++c) {
            float wgt = fexp2(m[c] - M);
            L += lv[c] * wgt;
            acc += wgt * (float)Opart[((size_t)(c * BB * NHEAD + head) * SS + q) * DKH + lane];
        }
        outv = acc / L;
    }
    Ctx[((size_t)(b * SS) + q) * DMOD + h * DKH + lane] = (_Float16)outv;
}

// ---------------- launcher ----------------
extern "C" void kernel_launch(void* const* d_in, const int* in_sizes, int n_in,
                              void* d_out, int out_size, void* d_ws, size_t ws_size,
                              hipStream_t stream) {
    const float* x  = (const float*)d_in[0];
    const int*  msk = (const int*)d_in[1];
    const float* Wq = (const float*)d_in[2];
    const float* bq = (const float*)d_in[3];
    const float* Wk = (const float*)d_in[4];
    const float* bk = (const float*)d_in[5];
    const float* Wv = (const float*)d_in[6];
    const float* bv = (const float*)d_in[7];
    const float* Wo = (const float*)d_in[8];
    const float* bo = (const float*)d_in[9];

    char* ws = (char*)d_ws;
    _Float16* Xb   = (_Float16*)(ws);                 // 4096x768            6,291,456 B
    _Float16* Wqkv = (_Float16*)(ws + 6291456);       // 2304x768            3,538,944 B
    _Float16* Wob  = (_Float16*)(ws + 9830400);       // 768x768             1,179,648 B
    _Float16* Qd   = (_Float16*)(ws + 11010048);      // 24 x 2048 x 64      6,291,456 B
    _Float16* Kd   = (_Float16*)(ws + 17301504);      // 24 x 2048 x 64      6,291,456 B
    _Float16* Vtd  = (_Float16*)(ws + 23592960);      // 24 x 64 x 2048      6,291,456 B
    _Float16* Ctxb = (_Float16*)(ws + 29884416);      // 4096x768            6,291,456 B
    _Float16* Opart= (_Float16*)(ws + 36175872);      // 2 x 24 x 2048 x 64 12,582,912 B
    float*    Mpart= (float*)   (ws + 48758784);      // 2 x 24 x 2048         393,216 B
    float*    Lpart= (float*)   (ws + 49152000);      // 2 x 24 x 2048         393,216 B

    k_cvtall<<<5376, 256, 0, stream>>>(x, Wq, Wk, Wv, Wo,
                                       Xb, Wqkv, Wqkv + 589824, Wqkv + 1179648, Wob);

    k_gemm<1><<<dim3(18, 32), 256, 0, stream>>>(Xb, Wqkv, bq, bk, bv,
                                                nullptr, Qd, Kd, Vtd, DMOD, 0);
    k_attn<<<dim3(24 * 16 * NCHUNK), 256, 0, stream>>>(Qd, Kd, Vtd, msk, Opart, Mpart, Lpart);
    k_merge<<<12288, 256, 0, stream>>>(Opart, Mpart, Lpart, Ctxb);
    k_gemm<0><<<dim3(6, 32), 256, 0, stream>>>(Ctxb, Wob, bo, nullptr, nullptr,
                                               (float*)d_out, nullptr, nullptr, nullptr,
                                               DMOD, DMOD);
}